// Round 14
// baseline (257.544 us; speedup 1.0000x reference)
//
#include <hip/hip_runtime.h>
#include <hip/hip_bf16.h>

#define B 2
#define S 2048
#define D 1024
#define H 16
#define DKh 64
#define DFF 4096
#define M (B*S)

typedef unsigned short u16;
typedef unsigned int u32;
typedef __attribute__((ext_vector_type(8))) short short8;
typedef __attribute__((ext_vector_type(4))) float f32x4;

__device__ __forceinline__ u16 f2bf(float f) {
  union { float f; unsigned u; } v; v.f = f;
  unsigned r = v.u + 0x7fffu + ((v.u >> 16) & 1u);
  return (u16)(r >> 16);
}

__device__ __forceinline__ float bf2f(u16 h) {
  union { u32 u; float f; } v; v.u = ((u32)h) << 16; return v.f;
}

// pack two f32 -> 2 bf16 (RTNE) in a u32 via the native conversion; the
// compiler emits v_cvt_pk_bf16_f32 for this pattern on gfx950.
__device__ __forceinline__ u32 pkbf2(float a, float b) {
  __hip_bfloat162 h = __float22bfloat162_rn(make_float2(a, b));
  return *reinterpret_cast<u32*>(&h);
}

__device__ __forceinline__ void gload16(const void* g, void* l) {
  __builtin_amdgcn_global_load_lds((const __attribute__((address_space(1))) void*)g,
                                   (__attribute__((address_space(3))) void*)l, 16, 0, 0);
}

#define SBAR()  __builtin_amdgcn_sched_barrier(0)
#define WBAR()  __builtin_amdgcn_s_barrier()

// ---------- fused prep: X->bf16 + 4 DxD W^T + W1^T + W2^T in ONE launch ----------
__device__ __forceinline__ void tcvt_body(const float* __restrict__ W,
    u16* __restrict__ Wt, int K, int N, int n0, int k0, u16 (*l)[65]) {
  const int tx = threadIdx.x & 63, ty = threadIdx.x >> 6;
#pragma unroll
  for (int j = 0; j < 16; ++j) {
    int r = j * 4 + ty;
    l[r][tx] = f2bf(W[(size_t)(k0 + r) * N + n0 + tx]);
  }
  __syncthreads();
#pragma unroll
  for (int j = 0; j < 16; ++j) {
    int r = j * 4 + ty;
    Wt[(size_t)(n0 + r) * K + k0 + tx] = l[tx][r];
  }
}

__global__ __launch_bounds__(256) void prep(const float* __restrict__ X,
    u16* __restrict__ Xb, const float* __restrict__ Wq, const float* __restrict__ Wk,
    const float* __restrict__ Wv, const float* __restrict__ Wo,
    u16* __restrict__ dQKV, u16* __restrict__ dO,
    const float* __restrict__ W1, u16* __restrict__ W1t,
    const float* __restrict__ W2, u16* __restrict__ W2t) {
  __shared__ u16 l[64][65];
  const int bid = blockIdx.x;
  if (bid < 4096) {
    int i = bid * 256 + threadIdx.x;
    float4 v = ((const float4*)X)[i];
    ushort4 o = make_ushort4(f2bf(v.x), f2bf(v.y), f2bf(v.z), f2bf(v.w));
    ((ushort4*)Xb)[i] = o;
  } else if (bid < 5120) {
    int bid2 = bid - 4096;
    int z = bid2 >> 8, r2 = bid2 & 255;
    const float* W = (z == 0) ? Wq : (z == 1) ? Wk : (z == 2) ? Wv : Wo;
    u16* Wt = (z < 3) ? dQKV + (size_t)z * D * D : dO;
    tcvt_body(W, Wt, D, D, (r2 & 15) * 64, (r2 >> 4) * 64, l);
  } else if (bid < 6144) {
    int r2 = bid - 5120;
    tcvt_body(W1, W1t, D, DFF, (r2 & 63) * 64, (r2 >> 6) * 64, l);
  } else {
    int r2 = bid - 6144;
    tcvt_body(W2, W2t, DFF, D, (r2 & 15) * 64, (r2 >> 4) * 64, l);
  }
}

// ================= 256x256 8-phase GEMM (T2+T3+T4+T5) =================
// C[M][N] = A[M][K] @ Bt[N][K]^T, bf16 in, BK=64, 8 waves (2Mx4N), 128KB LDS.
// EPI: 0 = bf16 store (cols < sCols scaled by qscl; cols >= 2048 optionally
// written TRANSPOSED to VtOut[b,h,dk,s] instead of Cout), 1 = f32 plane store
// (split-K via blockIdx.z), 2 = bias+relu bf16.
template<int EPI>
__global__ __launch_bounds__(512, 2) void gemm256(const u16* __restrict__ Ag,
    const u16* __restrict__ Bg, void* __restrict__ Cout,
    const float* __restrict__ bias, int Mm, int N, int ld, int Kper,
    int sCols, float qscl, u16* __restrict__ VtOut) {
  __shared__ u16 lA[2 * 16384];   // [2 buf][2 half][128 rh][64 k]
  __shared__ u16 lB[2 * 16384];
  const int t = threadIdx.x;
  const int lane = t & 63, w = t >> 6;
  const int wm = w >> 2, wn = w & 3;
  const int g = lane >> 4, c = lane & 15;
  const int swz = (c & 7) << 4;              // read-side byte swizzle

  // bijective XCD swizzle (per-plane nwg is a multiple of 8 in all launches)
  const int gx = gridDim.x, gy = gridDim.y;
  const int orig = blockIdx.y * gx + blockIdx.x;
  const int qchunk = (gx * gy) >> 3;
  const int wg = (orig & 7) * qchunk + (orig >> 3);
  const int bn0 = (wg % gx) * 256, bm0 = (wg / gx) * 256;
  const int koff = blockIdx.z * Kper;
  const int nk = Kper >> 6;

  f32x4 acc[8][4] = {};
  short8 af[4][2], bf[2][2];

  auto stageA = [&](int h, int buf, int kt) {
#pragma unroll
    for (int i = 0; i < 2; ++i) {
      int chunk = i * 512 + t;
      int rh = chunk >> 3;
      int cb = (chunk & 7) * 16;
      int r = (rh & 63) + (h + 2 * (rh >> 6)) * 64;
      gload16(Ag + (size_t)(bm0 + r) * ld + koff + kt * 64 + ((cb ^ ((r & 7) << 4)) >> 1),
              (void*)((char*)lA + buf * 32768 + h * 16384 + chunk * 16));
    }
  };
  auto stageB = [&](int h, int buf, int kt) {
#pragma unroll
    for (int i = 0; i < 2; ++i) {
      int chunk = i * 512 + t;
      int rh = chunk >> 3;
      int cb = (chunk & 7) * 16;
      int r = (rh & 31) + (h + 2 * (rh >> 5)) * 32;
      gload16(Bg + (size_t)(bn0 + r) * ld + koff + kt * 64 + ((cb ^ ((r & 7) << 4)) >> 1),
              (void*)((char*)lB + buf * 32768 + h * 16384 + chunk * 16));
    }
  };

#define RDA(mh) { const char* lab = (const char*)lA + cur * 32768;                          \
  _Pragma("unroll") for (int mt2 = 0; mt2 < 4; ++mt2)                                       \
    _Pragma("unroll") for (int kc = 0; kc < 2; ++kc)                                        \
      af[mt2][kc] = *(const short8*)(lab + (wm * 64 + (mh) * 128 + mt2 * 16 + c) * 128      \
                                         + ((kc * 64 + g * 16) ^ swz)); }
#define RDB(nh) { const char* lbb = (const char*)lB + cur * 32768;                          \
  _Pragma("unroll") for (int nt2 = 0; nt2 < 2; ++nt2)                                       \
    _Pragma("unroll") for (int kc = 0; kc < 2; ++kc)                                        \
      bf[nt2][kc] = *(const short8*)(lbb + ((nh) * 128 + wn * 32 + nt2 * 16 + c) * 128      \
                                         + ((kc * 64 + g * 16) ^ swz)); }
#define QMFMA(mh, nh) { __builtin_amdgcn_s_setprio(1);                                      \
  _Pragma("unroll") for (int mt2 = 0; mt2 < 4; ++mt2)                                       \
    _Pragma("unroll") for (int nt2 = 0; nt2 < 2; ++nt2)                                     \
      _Pragma("unroll") for (int kc = 0; kc < 2; ++kc)                                      \
        acc[(mh) * 4 + mt2][(nh) * 2 + nt2] = __builtin_amdgcn_mfma_f32_16x16x32_bf16(      \
            af[mt2][kc], bf[nt2][kc], acc[(mh) * 4 + mt2][(nh) * 2 + nt2], 0, 0, 0);        \
  __builtin_amdgcn_s_setprio(0); }

  // prologue: stage tile 0 (A0,B0,A1,B1), ensure A0,B0 landed (A1,B1 in flight)
  stageA(0, 0, 0); stageB(0, 0, 0); stageA(1, 0, 0); stageB(1, 0, 0);
  asm volatile("s_waitcnt vmcnt(4)" ::: "memory");
  SBAR(); WBAR(); SBAR();

  int cur = 0;
  for (int kt = 0; kt < nk; ++kt) {
    const bool more = (kt + 1 < nk);
    // ---- phase 0: reads A0,B0 of tile kt; stages A0' ----
    RDB(0); RDA(0);
    if (more) { stageA(0, cur ^ 1, kt + 1);
                asm volatile("s_waitcnt vmcnt(4)" ::: "memory"); }   // ensure A1(kt)
    else      { asm volatile("s_waitcnt vmcnt(2)" ::: "memory"); }
    SBAR(); WBAR(); SBAR();
    QMFMA(0, 0);
    SBAR(); WBAR(); SBAR();
    // ---- phase 1: reads A1; stages B0' ----
    RDA(1);
    if (more) { stageB(0, cur ^ 1, kt + 1);
                asm volatile("s_waitcnt vmcnt(4)" ::: "memory"); }   // ensure B1(kt)
    else      { asm volatile("s_waitcnt vmcnt(0)" ::: "memory"); }
    SBAR(); WBAR(); SBAR();
    QMFMA(1, 0);
    SBAR(); WBAR(); SBAR();
    // ---- phase 2: reads B1; stages A1' (no wait needed) ----
    RDB(1);
    if (more) stageA(1, cur ^ 1, kt + 1);
    SBAR(); WBAR(); SBAR();
    QMFMA(1, 1);
    SBAR(); WBAR(); SBAR();
    // ---- phase 3: re-reads A0; stages B1' ----
    RDA(0);
    if (more) { stageB(1, cur ^ 1, kt + 1);
                asm volatile("s_waitcnt vmcnt(4)" ::: "memory"); }   // ensure A0',B0'
    SBAR(); WBAR(); SBAR();
    QMFMA(0, 1);
    SBAR(); WBAR(); SBAR();
    cur ^= 1;
  }
#undef RDA
#undef RDB
#undef QMFMA

  // epilogue
  float* plane = (EPI == 1) ? ((float*)Cout + (size_t)blockIdx.z * Mm * N) : (float*)Cout;
#pragma unroll
  for (int mt = 0; mt < 8; ++mt) {
#pragma unroll
    for (int nt = 0; nt < 4; ++nt) {
      const int col = bn0 + wn * 64 + nt * 16 + c;
      float bv = (EPI == 2) ? bias[col] : 0.0f;
#pragma unroll
      for (int r = 0; r < 4; ++r) {
        const int row = bm0 + wm * 128 + mt * 16 + g * 4 + r;
        float v = acc[mt][nt][r];
        if (EPI == 2) v = fmaxf(v + bv, 0.0f);
        if (EPI == 0 && col < sCols) v *= qscl;   // fold attn scale into Q (f32, exact)
        if (EPI == 1) {
          plane[(size_t)row * N + col] = v;
        } else if (EPI == 0 && VtOut && col >= 2 * D) {
          // V columns: write transposed into Vt[b,h,dk,s] (s = row & (S-1))
          const int dkk = col - 2 * D;
          VtOut[((size_t)((row >> 11) * H + (dkk >> 6)) * DKh + (dkk & 63)) * S + (row & 2047)] = f2bf(v);
        } else {
          ((u16*)Cout)[(size_t)row * N + col] = f2bf(v);
        }
      }
    }
  }
}

// ---- flash attention: proven R12 body — 2 Q-sets per wave (128 q/block) ----
// K/V LDS fragments shared by both sets; 40KB LDS keeps 2+ blocks/CU.
__global__ __launch_bounds__(256) void attn_kernel(const u16* __restrict__ Q,
    const u16* __restrict__ Kp, const u16* __restrict__ Vt,
    const int* __restrict__ mask, u16* __restrict__ Ctx, int ldq) {
  __shared__ u16 lK[2][64 * 64];
  __shared__ u16 lV[2][64 * 64];
  __shared__ u16 lP[4 * 16 * 64];
  const int t = threadIdx.x, lane = t & 63, w = t >> 6;
  const int g = lane >> 4, c = lane & 15;
  const int gx = gridDim.x;
  const int orig = blockIdx.y * gx + blockIdx.x;
  const int qchunk = (gx * gridDim.y) >> 3;
  const int wg = (orig & 7) * qchunk + (orig >> 3);
  const int bx = wg % gx, by = wg / gx;           // q-tile(128), b*H+h
  const int b = by >> 4, h = by & 15;
  const int q0w = bx * 128 + w * 16;              // set 0; set 1 at +64

  short8 qf[2][2];
#pragma unroll
  for (int s = 0; s < 2; ++s)
#pragma unroll
    for (int kc = 0; kc < 2; ++kc)
      qf[s][kc] = *(const short8*)&Q[(size_t)(b * S + q0w + s * 64 + c) * ldq + h * DKh + kc * 32 + g * 8];

  float lsum0 = 0.0f, lsum1 = 0.0f;
  f32x4 accO0[4] = {}, accO1[4] = {};

  auto stage = [&](int buf, int it) {
    const int kv0 = it * 64;
#pragma unroll
    for (int q = 0; q < 2; ++q) {
      int idx = q * 256 + t;
      int row = idx >> 3;
      int colb = (idx & 7) * 16;
      int scol = colb ^ ((row & 7) << 4);         // bytes, pre-swizzled source
      gload16(Kp + (size_t)(b * S + kv0 + row) * ldq + h * DKh + scol / 2,
              (void*)(&lK[buf][0] + idx * 8));
      gload16(Vt + (size_t)(by * 64 + row) * S + kv0 + scol / 2,
              (void*)(&lV[buf][0] + idx * 8));
    }
  };

  stage(0, 0);
  int cur = 0;
  for (int it = 0; it < S / 64; ++it) {
    __syncthreads();  // buf[cur] staged (vmcnt drained), prev reads of buf[cur^1] done
    if (it + 1 < S / 64) stage(cur ^ 1, it + 1);   // overlap with compute

    // --- QK^T both sets; K fragment read ONCE per ct, feeds 4 MFMAs ---
    f32x4 sc0[4], sc1[4];
#pragma unroll
    for (int ct = 0; ct < 4; ++ct) {
      int row = ct * 16 + c;
      short8 kf0 = *(const short8*)&lK[cur][row * 64 + (((0 * 64 + g * 16) ^ ((row & 7) << 4)) >> 1)];
      short8 kf1 = *(const short8*)&lK[cur][row * 64 + (((1 * 64 + g * 16) ^ ((row & 7) << 4)) >> 1)];
      f32x4 z0 = {0.f, 0.f, 0.f, 0.f};
      z0 = __builtin_amdgcn_mfma_f32_16x16x32_bf16(kf0, qf[0][0], z0, 0, 0, 0);
      z0 = __builtin_amdgcn_mfma_f32_16x16x32_bf16(kf1, qf[0][1], z0, 0, 0, 0);
      sc0[ct] = z0;
      f32x4 z1 = {0.f, 0.f, 0.f, 0.f};
      z1 = __builtin_amdgcn_mfma_f32_16x16x32_bf16(kf0, qf[1][0], z1, 0, 0, 0);
      z1 = __builtin_amdgcn_mfma_f32_16x16x32_bf16(kf1, qf[1][1], z1, 0, 0, 0);
      sc1[ct] = z1;
    }

    // --- softmax numerators (Q pre-scaled upstream), pack, P round-trips ---
    short8 pa0[2], pa1[2];
#pragma unroll
    for (int ct = 0; ct < 4; ++ct) {
      float p0 = __builtin_amdgcn_exp2f(sc0[ct][0]);
      float p1 = __builtin_amdgcn_exp2f(sc0[ct][1]);
      float p2 = __builtin_amdgcn_exp2f(sc0[ct][2]);
      float p3 = __builtin_amdgcn_exp2f(sc0[ct][3]);
      lsum0 += (p0 + p1) + (p2 + p3);
      uint2 pk;
      pk.x = pkbf2(p0, p1);
      pk.y = pkbf2(p2, p3);
      *(uint2*)&lP[w * 1024 + c * 64 + (((ct * 32 + g * 8) ^ ((c & 7) << 4)) >> 1)] = pk;
    }
#pragma unroll
    for (int kc = 0; kc < 2; ++kc)
      pa0[kc] = *(const short8*)&lP[w * 1024 + c * 64 + (((kc * 64 + g * 16) ^ ((c & 7) << 4)) >> 1)];
#pragma unroll
    for (int ct = 0; ct < 4; ++ct) {
      float p0 = __builtin_amdgcn_exp2f(sc1[ct][0]);
      float p1 = __builtin_amdgcn_exp2f(sc1[ct][1]);
      float p2 = __builtin_amdgcn_exp2f(sc1[ct][2]);
      float p3 = __builtin_amdgcn_exp2f(sc1[ct][3]);
      lsum1 += (p0 + p1) + (p2 + p3);
      uint2 pk;
      pk.x = pkbf2(p0, p1);
      pk.y = pkbf2(p2, p3);
      *(uint2*)&lP[w * 1024 + c * 64 + (((ct * 32 + g * 8) ^ ((c & 7) << 4)) >> 1)] = pk;
    }
#pragma unroll
    for (int kc = 0; kc < 2; ++kc)
      pa1[kc] = *(const short8*)&lP[w * 1024 + c * 64 + (((kc * 64 + g * 16) ^ ((c & 7) << 4)) >> 1)];
    // in-order DS per wave: pa0 reads execute before set-1 overwrites land

    // --- PV both sets; V fragment read ONCE per (dt,kc), feeds 2 MFMAs ---
#pragma unroll
    for (int dt = 0; dt < 4; ++dt) {
#pragma unroll
      for (int kc = 0; kc < 2; ++kc) {
        int rowV = dt * 16 + c;
        int bcolV = (kc * 64 + g * 16) ^ ((rowV & 7) << 4);
        short8 vb = *(const short8*)&lV[cur][rowV * 64 + bcolV / 2];
        accO0[dt] = __builtin_amdgcn_mfma_f32_16x16x32_bf16(pa0[kc], vb, accO0[dt], 0, 0, 0);
        accO1[dt] = __builtin_amdgcn_mfma_f32_16x16x32_bf16(pa1[kc], vb, accO1[dt], 0, 0, 0);
      }
    }
    cur ^= 1;
  }

  // --- reduce l across g-groups (once per kernel) ---
  lsum0 += __shfl_xor(lsum0, 16);
  lsum0 += __shfl_xor(lsum0, 32);
  lsum1 += __shfl_xor(lsum1, 16);
  lsum1 += __shfl_xor(lsum1, 32);

  // epilogue: O = accO / l, zero masked query rows (both sets)
#pragma unroll
  for (int r = 0; r < 4; ++r) {
    int qrow = g * 4 + r;
    float lq0 = __shfl(lsum0, qrow);
    float lq1 = __shfl(lsum1, qrow);
    int q0 = q0w + qrow;
    int q1 = q0w + 64 + qrow;
    float inv0 = (mask[b * S + q0] != 0) ? (1.0f / lq0) : 0.0f;
    float inv1 = (mask[b * S + q1] != 0) ? (1.0f / lq1) : 0.0f;
#pragma unroll
    for (int dt = 0; dt < 4; ++dt) {
      Ctx[(size_t)(b * S + q0) * D + h * DKh + dt * 16 + c] = f2bf(accO0[dt][r] * inv0);
      Ctx[(size_t)(b * S + q1) * D + h * DKh + dt * 16 + c] = f2bf(accO1[dt][r] * inv1);
    }
  }
}

// ---- residual + LayerNorm: out = Xres + LN(sum planes [+bias])*gamma+beta ----
// Xres from f32 (XresF) or bf16 (XresB); outputs f32 (outF) and/or bf16 (outB).
__global__ __launch_bounds__(256) void ln_res(const float* __restrict__ planes,
    int np, const float* __restrict__ bias, const float* __restrict__ XresF,
    const u16* __restrict__ XresB, const float* __restrict__ gamma,
    const float* __restrict__ beta, float* __restrict__ outF,
    u16* __restrict__ outB) {
  __shared__ float s1[4], s2[4];
  const int row = blockIdx.x, t = threadIdx.x;
  float4 y = ((const float4*)(planes + (size_t)row * D))[t];
  for (int j = 1; j < np; ++j) {
    const float4 y2 = ((const float4*)(planes + (size_t)j * M * D + (size_t)row * D))[t];
    y.x += y2.x; y.y += y2.y; y.z += y2.z; y.w += y2.w;
  }
  if (bias) {
    const float4 bb = ((const float4*)bias)[t];
    y.x += bb.x; y.y += bb.y; y.z += bb.z; y.w += bb.w;
  }
  float sm = y.x + y.y + y.z + y.w;
  float sq = y.x * y.x + y.y * y.y + y.z * y.z + y.w * y.w;
#pragma unroll
  for (int m2 = 1; m2 <= 32; m2 <<= 1) { sm += __shfl_xor(sm, m2); sq += __shfl_xor(sq, m2); }
  if ((t & 63) == 0) { s1[t >> 6] = sm; s2[t >> 6] = sq; }
  __syncthreads();
  float tot = s1[0] + s1[1] + s1[2] + s1[3];
  float tsq = s2[0] + s2[1] + s2[2] + s2[3];
  float mu = tot * (1.0f / D);
  float var = tsq * (1.0f / D) - mu * mu;
  float rstd = rsqrtf(var + 1e-6f);
  float4 xr;
  if (XresF) {
    xr = ((const float4*)(XresF + (size_t)row * D))[t];
  } else {
    ushort4 xb = ((const ushort4*)(XresB + (size_t)row * D))[t];
    xr.x = bf2f(xb.x); xr.y = bf2f(xb.y); xr.z = bf2f(xb.z); xr.w = bf2f(xb.w);
  }
  const float4 ga = ((const float4*)gamma)[t];
  const float4 be = ((const float4*)beta)[t];
  float4 o;
  o.x = xr.x + (y.x - mu) * rstd * ga.x + be.x;
  o.y = xr.y + (y.y - mu) * rstd * ga.y + be.y;
  o.z = xr.z + (y.z - mu) * rstd * ga.z + be.z;
  o.w = xr.w + (y.w - mu) * rstd * ga.w + be.w;
  if (outF) ((float4*)(outF + (size_t)row * D))[t] = o;
  if (outB) {
    ushort4 ob = make_ushort4(f2bf(o.x), f2bf(o.y), f2bf(o.z), f2bf(o.w));
    ((ushort4*)outB)[(size_t)row * (D / 4) + t] = ob;
  }
}

extern "C" void kernel_launch(void* const* d_in, const int* in_sizes, int n_in,
                              void* d_out, int out_size, void* d_ws, size_t ws_size,
                              hipStream_t stream) {
  const float* X   = (const float*)d_in[0];
  const int*   msk = (const int*)d_in[1];
  const float* WQ  = (const float*)d_in[2];
  const float* WK  = (const float*)d_in[3];
  const float* WV  = (const float*)d_in[4];
  const float* WO  = (const float*)d_in[5];
  const float* W1  = (const float*)d_in[6];
  const float* b1  = (const float*)d_in[7];
  const float* W2  = (const float*)d_in[8];
  const float* b2  = (const float*)d_in[9];
  const float* g1  = (const float*)d_in[10];
  const float* be1 = (const float*)d_in[11];
  const float* g2  = (const float*)d_in[12];
  const float* be2 = (const float*)d_in[13];
  float* out = (float*)d_out;
  const float SCL = 0.18033688011112042f;   // log2(e) / sqrt(DKh)

  char* ws = (char*)d_ws;
  size_t off = 0;
  auto alloc = [&](size_t bytes) {
    void* p = ws + off;
    off += (bytes + 1023) & ~(size_t)1023;
    return p;
  };
  u16* Xb     = (u16*)alloc((size_t)M * D * 2);           // 8 MB
  u16* WQKVt  = (u16*)alloc((size_t)3 * D * D * 2);       // 6 MB
  u16* WOt    = (u16*)alloc((size_t)D * D * 2);           // 2 MB
  u16* W1t    = (u16*)alloc((size_t)DFF * D * 2);         // 8 MB
  u16* W2t    = (u16*)alloc((size_t)D * DFF * 2);         // 8 MB
  u16* QKVb   = (u16*)alloc((size_t)M * 3 * D * 2);       // 24 MB
  u16* Vt     = (u16*)alloc((size_t)B * H * DKh * S * 2); // 8 MB (contiguous after QKVb)
  u16* Ctx    = (u16*)alloc((size_t)M * D * 2);           // 8 MB
  u16* X1b    = (u16*)alloc((size_t)M * D * 2);           // 8 MB (x1, bf16 only)
  u16* Hb     = (u16*)alloc((size_t)M * DFF * 2);         // 32 MB
  // 2-plane split-K scratch aliases QKVb+Vt (32 MB contiguous, dead post-attn).
  float* PP   = (float*)QKVb;
  if (off > ws_size) return;  // mandatory allocs must fit
  // optional dedicated 64 MB for 4-plane split-K of W2
  size_t off4 = off;
  float* PP4 = (float*)(ws + off4);
  off4 += (size_t)4 * M * D * 4;
  const bool split4 = (off4 <= ws_size);

  dim3 blk(256), blk5(512);

  // 1+2. fused prep: X->bf16, all weight transposes, one launch
  prep<<<dim3(7168), blk, 0, stream>>>(X, Xb, WQ, WK, WV, WO, WQKVt, WOt, W1, W1t, W2, W2t);
  // 3. fused QKV projection: [4096][3072]; Q cols (<D) pre-scaled by log2(e)/8;
  //    V cols written transposed directly into Vt (vtrans fused away).
  gemm256<0><<<dim3(3 * D / 256, M / 256), blk5, 0, stream>>>(Xb, WQKVt, QKVb, nullptr, M, 3 * D, D, D, D, SCL, Vt);
  // 4. attention (2 Q-sets per wave, 128 q/block -> 512 blocks; proven R12 body)
  attn_kernel<<<dim3(S / 128, B * H), blk, 0, stream>>>(QKVb, QKVb + D, Vt, msk, Ctx, 3 * D);
  // 5. O projection, split-K=2 -> planes PP[0..1] (QKVb region dead)
  gemm256<1><<<dim3(D / 256, M / 256, 2), blk5, 0, stream>>>(Ctx, WOt, PP, nullptr, M, D, D, D / 2, 0, 1.0f, nullptr);
  // 6. x1 = X + LN(AO0+AO1)  (bf16 only)
  ln_res<<<dim3(M), blk, 0, stream>>>(PP, 2, nullptr, X, nullptr, g1, be1, nullptr, X1b);
  // 7. H = relu(x1 @ W1 + b1)
  gemm256<2><<<dim3(DFF / 256, M / 256), blk5, 0, stream>>>(X1b, W1t, Hb, b1, M, DFF, D, D, 0, 1.0f, nullptr);
  // 8/9. ffn = H @ W2 (split-K), then out = x1 + LN(sum planes + b2)
  if (split4) {
    gemm256<1><<<dim3(D / 256, M / 256, 4), blk5, 0, stream>>>(Hb, W2t, PP4, nullptr, M, D, DFF, DFF / 4, 0, 1.0f, nullptr);
    ln_res<<<dim3(M), blk, 0, stream>>>(PP4, 4, b2, nullptr, X1b, g2, be2, out, nullptr);
  } else {
    gemm256<1><<<dim3(D / 256, M / 256, 2), blk5, 0, stream>>>(Hb, W2t, PP, nullptr, M, D, DFF, DFF / 2, 0, 1.0f, nullptr);
    ln_res<<<dim3(M), blk, 0, stream>>>(PP, 2, b2, nullptr, X1b, g2, be2, out, nullptr);
  }
}

// Round 15
// 236.727 us; speedup vs baseline: 1.0879x; 1.0879x over previous
//
#include <hip/hip_runtime.h>
#include <hip/hip_bf16.h>

#define B 2
#define S 2048
#define D 1024
#define H 16
#define DKh 64
#define DFF 4096
#define M (B*S)

typedef unsigned short u16;
typedef unsigned int u32;
typedef __attribute__((ext_vector_type(8))) short short8;
typedef __attribute__((ext_vector_type(4))) float f32x4;

__device__ __forceinline__ u16 f2bf(float f) {
  union { float f; unsigned u; } v; v.f = f;
  unsigned r = v.u + 0x7fffu + ((v.u >> 16) & 1u);
  return (u16)(r >> 16);
}

__device__ __forceinline__ float bf2f(u16 h) {
  union { u32 u; float f; } v; v.u = ((u32)h) << 16; return v.f;
}

// pack two f32 -> 2 bf16 (RTNE) in a u32 via the native conversion; the
// compiler emits v_cvt_pk_bf16_f32 for this pattern on gfx950.
__device__ __forceinline__ u32 pkbf2(float a, float b) {
  __hip_bfloat162 h = __float22bfloat162_rn(make_float2(a, b));
  return *reinterpret_cast<u32*>(&h);
}

__device__ __forceinline__ void gload16(const void* g, void* l) {
  __builtin_amdgcn_global_load_lds((const __attribute__((address_space(1))) void*)g,
                                   (__attribute__((address_space(3))) void*)l, 16, 0, 0);
}

#define SBAR()  __builtin_amdgcn_sched_barrier(0)
#define WBAR()  __builtin_amdgcn_s_barrier()

// ---------- fused prep: X->bf16 + 4 DxD W^T + W1^T + W2^T in ONE launch ----------
__device__ __forceinline__ void tcvt_body(const float* __restrict__ W,
    u16* __restrict__ Wt, int K, int N, int n0, int k0, u16 (*l)[65]) {
  const int tx = threadIdx.x & 63, ty = threadIdx.x >> 6;
#pragma unroll
  for (int j = 0; j < 16; ++j) {
    int r = j * 4 + ty;
    l[r][tx] = f2bf(W[(size_t)(k0 + r) * N + n0 + tx]);
  }
  __syncthreads();
#pragma unroll
  for (int j = 0; j < 16; ++j) {
    int r = j * 4 + ty;
    Wt[(size_t)(n0 + r) * K + k0 + tx] = l[tx][r];
  }
}

__global__ __launch_bounds__(256) void prep(const float* __restrict__ X,
    u16* __restrict__ Xb, const float* __restrict__ Wq, const float* __restrict__ Wk,
    const float* __restrict__ Wv, const float* __restrict__ Wo,
    u16* __restrict__ dQKV, u16* __restrict__ dO,
    const float* __restrict__ W1, u16* __restrict__ W1t,
    const float* __restrict__ W2, u16* __restrict__ W2t) {
  __shared__ u16 l[64][65];
  const int bid = blockIdx.x;
  if (bid < 4096) {
    int i = bid * 256 + threadIdx.x;
    float4 v = ((const float4*)X)[i];
    ushort4 o = make_ushort4(f2bf(v.x), f2bf(v.y), f2bf(v.z), f2bf(v.w));
    ((ushort4*)Xb)[i] = o;
  } else if (bid < 5120) {
    int bid2 = bid - 4096;
    int z = bid2 >> 8, r2 = bid2 & 255;
    const float* W = (z == 0) ? Wq : (z == 1) ? Wk : (z == 2) ? Wv : Wo;
    u16* Wt = (z < 3) ? dQKV + (size_t)z * D * D : dO;
    tcvt_body(W, Wt, D, D, (r2 & 15) * 64, (r2 >> 4) * 64, l);
  } else if (bid < 6144) {
    int r2 = bid - 5120;
    tcvt_body(W1, W1t, D, DFF, (r2 & 63) * 64, (r2 >> 6) * 64, l);
  } else {
    int r2 = bid - 6144;
    tcvt_body(W2, W2t, DFF, D, (r2 & 15) * 64, (r2 >> 4) * 64, l);
  }
}

// ---------------- bf16 V [b,s,(h,dk)] (ld) -> Vt [b,h,dk,s] ----------------
__global__ __launch_bounds__(256) void vtrans(const u16* __restrict__ V,
                                              u16* __restrict__ Vt, int ld) {
  __shared__ u16 l[64][65];
  const int s0 = blockIdx.x * 64, by = blockIdx.y;  // by = b*H+h
  const int b = by >> 4, h = by & 15;
  const int tx = threadIdx.x & 63, ty = threadIdx.x >> 6;
#pragma unroll
  for (int j = 0; j < 16; ++j) {
    int r = j * 4 + ty;  // s index
    l[r][tx] = V[(size_t)(b * S + s0 + r) * ld + h * DKh + tx];
  }
  __syncthreads();
#pragma unroll
  for (int j = 0; j < 16; ++j) {
    int r = j * 4 + ty;  // dk index
    Vt[(size_t)(by * 64 + r) * S + s0 + tx] = l[tx][r];
  }
}

// ================= 256x256 8-phase GEMM (T2+T3+T4+T5) =================
// C[M][N] = A[M][K] @ Bt[N][K]^T, bf16 in, BK=64, 8 waves (2Mx4N), 128KB LDS.
// EPI: 0 = bf16 store (cols < sCols scaled by qscl), 1 = f32 plane store
// (split-K via blockIdx.z), 2 = bias+relu bf16.
template<int EPI>
__global__ __launch_bounds__(512, 2) void gemm256(const u16* __restrict__ Ag,
    const u16* __restrict__ Bg, void* __restrict__ Cout,
    const float* __restrict__ bias, int Mm, int N, int ld, int Kper,
    int sCols, float qscl) {
  __shared__ u16 lA[2 * 16384];   // [2 buf][2 half][128 rh][64 k]
  __shared__ u16 lB[2 * 16384];
  const int t = threadIdx.x;
  const int lane = t & 63, w = t >> 6;
  const int wm = w >> 2, wn = w & 3;
  const int g = lane >> 4, c = lane & 15;
  const int swz = (c & 7) << 4;              // read-side byte swizzle

  // bijective XCD swizzle (per-plane nwg is a multiple of 8 in all launches)
  const int gx = gridDim.x, gy = gridDim.y;
  const int orig = blockIdx.y * gx + blockIdx.x;
  const int qchunk = (gx * gy) >> 3;
  const int wg = (orig & 7) * qchunk + (orig >> 3);
  const int bn0 = (wg % gx) * 256, bm0 = (wg / gx) * 256;
  const int koff = blockIdx.z * Kper;
  const int nk = Kper >> 6;

  f32x4 acc[8][4] = {};
  short8 af[4][2], bf[2][2];

  auto stageA = [&](int h, int buf, int kt) {
#pragma unroll
    for (int i = 0; i < 2; ++i) {
      int chunk = i * 512 + t;
      int rh = chunk >> 3;
      int cb = (chunk & 7) * 16;
      int r = (rh & 63) + (h + 2 * (rh >> 6)) * 64;
      gload16(Ag + (size_t)(bm0 + r) * ld + koff + kt * 64 + ((cb ^ ((r & 7) << 4)) >> 1),
              (void*)((char*)lA + buf * 32768 + h * 16384 + chunk * 16));
    }
  };
  auto stageB = [&](int h, int buf, int kt) {
#pragma unroll
    for (int i = 0; i < 2; ++i) {
      int chunk = i * 512 + t;
      int rh = chunk >> 3;
      int cb = (chunk & 7) * 16;
      int r = (rh & 31) + (h + 2 * (rh >> 5)) * 32;
      gload16(Bg + (size_t)(bn0 + r) * ld + koff + kt * 64 + ((cb ^ ((r & 7) << 4)) >> 1),
              (void*)((char*)lB + buf * 32768 + h * 16384 + chunk * 16));
    }
  };

#define RDA(mh) { const char* lab = (const char*)lA + cur * 32768;                          \
  _Pragma("unroll") for (int mt2 = 0; mt2 < 4; ++mt2)                                       \
    _Pragma("unroll") for (int kc = 0; kc < 2; ++kc)                                        \
      af[mt2][kc] = *(const short8*)(lab + (wm * 64 + (mh) * 128 + mt2 * 16 + c) * 128      \
                                         + ((kc * 64 + g * 16) ^ swz)); }
#define RDB(nh) { const char* lbb = (const char*)lB + cur * 32768;                          \
  _Pragma("unroll") for (int nt2 = 0; nt2 < 2; ++nt2)                                       \
    _Pragma("unroll") for (int kc = 0; kc < 2; ++kc)                                        \
      bf[nt2][kc] = *(const short8*)(lbb + ((nh) * 128 + wn * 32 + nt2 * 16 + c) * 128      \
                                         + ((kc * 64 + g * 16) ^ swz)); }
#define QMFMA(mh, nh) { __builtin_amdgcn_s_setprio(1);                                      \
  _Pragma("unroll") for (int mt2 = 0; mt2 < 4; ++mt2)                                       \
    _Pragma("unroll") for (int nt2 = 0; nt2 < 2; ++nt2)                                     \
      _Pragma("unroll") for (int kc = 0; kc < 2; ++kc)                                      \
        acc[(mh) * 4 + mt2][(nh) * 2 + nt2] = __builtin_amdgcn_mfma_f32_16x16x32_bf16(      \
            af[mt2][kc], bf[nt2][kc], acc[(mh) * 4 + mt2][(nh) * 2 + nt2], 0, 0, 0);        \
  __builtin_amdgcn_s_setprio(0); }

  // prologue: stage tile 0 (A0,B0,A1,B1), ensure A0,B0 landed (A1,B1 in flight)
  stageA(0, 0, 0); stageB(0, 0, 0); stageA(1, 0, 0); stageB(1, 0, 0);
  asm volatile("s_waitcnt vmcnt(4)" ::: "memory");
  SBAR(); WBAR(); SBAR();

  int cur = 0;
  for (int kt = 0; kt < nk; ++kt) {
    const bool more = (kt + 1 < nk);
    // ---- phase 0: reads A0,B0 of tile kt; stages A0' ----
    RDB(0); RDA(0);
    if (more) { stageA(0, cur ^ 1, kt + 1);
                asm volatile("s_waitcnt vmcnt(4)" ::: "memory"); }   // ensure A1(kt)
    else      { asm volatile("s_waitcnt vmcnt(2)" ::: "memory"); }
    SBAR(); WBAR(); SBAR();
    QMFMA(0, 0);
    SBAR(); WBAR(); SBAR();
    // ---- phase 1: reads A1; stages B0' ----
    RDA(1);
    if (more) { stageB(0, cur ^ 1, kt + 1);
                asm volatile("s_waitcnt vmcnt(4)" ::: "memory"); }   // ensure B1(kt)
    else      { asm volatile("s_waitcnt vmcnt(0)" ::: "memory"); }
    SBAR(); WBAR(); SBAR();
    QMFMA(1, 0);
    SBAR(); WBAR(); SBAR();
    // ---- phase 2: reads B1; stages A1' (no wait needed) ----
    RDB(1);
    if (more) stageA(1, cur ^ 1, kt + 1);
    SBAR(); WBAR(); SBAR();
    QMFMA(1, 1);
    SBAR(); WBAR(); SBAR();
    // ---- phase 3: re-reads A0; stages B1' ----
    RDA(0);
    if (more) { stageB(1, cur ^ 1, kt + 1);
                asm volatile("s_waitcnt vmcnt(4)" ::: "memory"); }   // ensure A0',B0'
    SBAR(); WBAR(); SBAR();
    QMFMA(0, 1);
    SBAR(); WBAR(); SBAR();
    cur ^= 1;
  }
#undef RDA
#undef RDB
#undef QMFMA

  // epilogue
  float* plane = (EPI == 1) ? ((float*)Cout + (size_t)blockIdx.z * Mm * N) : (float*)Cout;
#pragma unroll
  for (int mt = 0; mt < 8; ++mt) {
#pragma unroll
    for (int nt = 0; nt < 4; ++nt) {
      const int col = bn0 + wn * 64 + nt * 16 + c;
      float bv = (EPI == 2) ? bias[col] : 0.0f;
#pragma unroll
      for (int r = 0; r < 4; ++r) {
        const int row = bm0 + wm * 128 + mt * 16 + g * 4 + r;
        float v = acc[mt][nt][r];
        if (EPI == 2) v = fmaxf(v + bv, 0.0f);
        if (EPI == 0 && col < sCols) v *= qscl;   // fold attn scale into Q (f32, exact)
        if (EPI == 1) plane[(size_t)row * N + col] = v;
        else          ((u16*)Cout)[(size_t)row * N + col] = f2bf(v);
      }
    }
  }
}

// ---- flash attention: proven R12 body — 2 Q-sets per wave (128 q/block) ----
// K/V LDS fragments shared by both sets; 40KB LDS keeps 2+ blocks/CU.
__global__ __launch_bounds__(256) void attn_kernel(const u16* __restrict__ Q,
    const u16* __restrict__ Kp, const u16* __restrict__ Vt,
    const int* __restrict__ mask, u16* __restrict__ Ctx, int ldq) {
  __shared__ u16 lK[2][64 * 64];
  __shared__ u16 lV[2][64 * 64];
  __shared__ u16 lP[4 * 16 * 64];
  const int t = threadIdx.x, lane = t & 63, w = t >> 6;
  const int g = lane >> 4, c = lane & 15;
  const int gx = gridDim.x;
  const int orig = blockIdx.y * gx + blockIdx.x;
  const int qchunk = (gx * gridDim.y) >> 3;
  const int wg = (orig & 7) * qchunk + (orig >> 3);
  const int bx = wg % gx, by = wg / gx;           // q-tile(128), b*H+h
  const int b = by >> 4, h = by & 15;
  const int q0w = bx * 128 + w * 16;              // set 0; set 1 at +64

  short8 qf[2][2];
#pragma unroll
  for (int s = 0; s < 2; ++s)
#pragma unroll
    for (int kc = 0; kc < 2; ++kc)
      qf[s][kc] = *(const short8*)&Q[(size_t)(b * S + q0w + s * 64 + c) * ldq + h * DKh + kc * 32 + g * 8];

  float lsum0 = 0.0f, lsum1 = 0.0f;
  f32x4 accO0[4] = {}, accO1[4] = {};

  auto stage = [&](int buf, int it) {
    const int kv0 = it * 64;
#pragma unroll
    for (int q = 0; q < 2; ++q) {
      int idx = q * 256 + t;
      int row = idx >> 3;
      int colb = (idx & 7) * 16;
      int scol = colb ^ ((row & 7) << 4);         // bytes, pre-swizzled source
      gload16(Kp + (size_t)(b * S + kv0 + row) * ldq + h * DKh + scol / 2,
              (void*)(&lK[buf][0] + idx * 8));
      gload16(Vt + (size_t)(by * 64 + row) * S + kv0 + scol / 2,
              (void*)(&lV[buf][0] + idx * 8));
    }
  };

  stage(0, 0);
  int cur = 0;
  for (int it = 0; it < S / 64; ++it) {
    __syncthreads();  // buf[cur] staged (vmcnt drained), prev reads of buf[cur^1] done
    if (it + 1 < S / 64) stage(cur ^ 1, it + 1);   // overlap with compute

    // --- QK^T both sets; K fragment read ONCE per ct, feeds 4 MFMAs ---
    f32x4 sc0[4], sc1[4];
#pragma unroll
    for (int ct = 0; ct < 4; ++ct) {
      int row = ct * 16 + c;
      short8 kf0 = *(const short8*)&lK[cur][row * 64 + (((0 * 64 + g * 16) ^ ((row & 7) << 4)) >> 1)];
      short8 kf1 = *(const short8*)&lK[cur][row * 64 + (((1 * 64 + g * 16) ^ ((row & 7) << 4)) >> 1)];
      f32x4 z0 = {0.f, 0.f, 0.f, 0.f};
      z0 = __builtin_amdgcn_mfma_f32_16x16x32_bf16(kf0, qf[0][0], z0, 0, 0, 0);
      z0 = __builtin_amdgcn_mfma_f32_16x16x32_bf16(kf1, qf[0][1], z0, 0, 0, 0);
      sc0[ct] = z0;
      f32x4 z1 = {0.f, 0.f, 0.f, 0.f};
      z1 = __builtin_amdgcn_mfma_f32_16x16x32_bf16(kf0, qf[1][0], z1, 0, 0, 0);
      z1 = __builtin_amdgcn_mfma_f32_16x16x32_bf16(kf1, qf[1][1], z1, 0, 0, 0);
      sc1[ct] = z1;
    }

    // --- softmax numerators (Q pre-scaled upstream), pack, P round-trips ---
    short8 pa0[2], pa1[2];
#pragma unroll
    for (int ct = 0; ct < 4; ++ct) {
      float p0 = __builtin_amdgcn_exp2f(sc0[ct][0]);
      float p1 = __builtin_amdgcn_exp2f(sc0[ct][1]);
      float p2 = __builtin_amdgcn_exp2f(sc0[ct][2]);
      float p3 = __builtin_amdgcn_exp2f(sc0[ct][3]);
      lsum0 += (p0 + p1) + (p2 + p3);
      uint2 pk;
      pk.x = pkbf2(p0, p1);
      pk.y = pkbf2(p2, p3);
      *(uint2*)&lP[w * 1024 + c * 64 + (((ct * 32 + g * 8) ^ ((c & 7) << 4)) >> 1)] = pk;
    }
#pragma unroll
    for (int kc = 0; kc < 2; ++kc)
      pa0[kc] = *(const short8*)&lP[w * 1024 + c * 64 + (((kc * 64 + g * 16) ^ ((c & 7) << 4)) >> 1)];
#pragma unroll
    for (int ct = 0; ct < 4; ++ct) {
      float p0 = __builtin_amdgcn_exp2f(sc1[ct][0]);
      float p1 = __builtin_amdgcn_exp2f(sc1[ct][1]);
      float p2 = __builtin_amdgcn_exp2f(sc1[ct][2]);
      float p3 = __builtin_amdgcn_exp2f(sc1[ct][3]);
      lsum1 += (p0 + p1) + (p2 + p3);
      uint2 pk;
      pk.x = pkbf2(p0, p1);
      pk.y = pkbf2(p2, p3);
      *(uint2*)&lP[w * 1024 + c * 64 + (((ct * 32 + g * 8) ^ ((c & 7) << 4)) >> 1)] = pk;
    }
#pragma unroll
    for (int kc = 0; kc < 2; ++kc)
      pa1[kc] = *(const short8*)&lP[w * 1024 + c * 64 + (((kc * 64 + g * 16) ^ ((c & 7) << 4)) >> 1)];
    // in-order DS per wave: pa0 reads execute before set-1 overwrites land

    // --- PV both sets; V fragment read ONCE per (dt,kc), feeds 2 MFMAs ---
#pragma unroll
    for (int dt = 0; dt < 4; ++dt) {
#pragma unroll
      for (int kc = 0; kc < 2; ++kc) {
        int rowV = dt * 16 + c;
        int bcolV = (kc * 64 + g * 16) ^ ((rowV & 7) << 4);
        short8 vb = *(const short8*)&lV[cur][rowV * 64 + bcolV / 2];
        accO0[dt] = __builtin_amdgcn_mfma_f32_16x16x32_bf16(pa0[kc], vb, accO0[dt], 0, 0, 0);
        accO1[dt] = __builtin_amdgcn_mfma_f32_16x16x32_bf16(pa1[kc], vb, accO1[dt], 0, 0, 0);
      }
    }
    cur ^= 1;
  }

  // --- reduce l across g-groups (once per kernel) ---
  lsum0 += __shfl_xor(lsum0, 16);
  lsum0 += __shfl_xor(lsum0, 32);
  lsum1 += __shfl_xor(lsum1, 16);
  lsum1 += __shfl_xor(lsum1, 32);

  // epilogue: O = accO / l, zero masked query rows (both sets)
#pragma unroll
  for (int r = 0; r < 4; ++r) {
    int qrow = g * 4 + r;
    float lq0 = __shfl(lsum0, qrow);
    float lq1 = __shfl(lsum1, qrow);
    int q0 = q0w + qrow;
    int q1 = q0w + 64 + qrow;
    float inv0 = (mask[b * S + q0] != 0) ? (1.0f / lq0) : 0.0f;
    float inv1 = (mask[b * S + q1] != 0) ? (1.0f / lq1) : 0.0f;
#pragma unroll
    for (int dt = 0; dt < 4; ++dt) {
      Ctx[(size_t)(b * S + q0) * D + h * DKh + dt * 16 + c] = f2bf(accO0[dt][r] * inv0);
      Ctx[(size_t)(b * S + q1) * D + h * DKh + dt * 16 + c] = f2bf(accO1[dt][r] * inv1);
    }
  }
}

// ---- residual + LayerNorm: out = Xres + LN(sum planes [+bias])*gamma+beta ----
// Xres from f32 (XresF) or bf16 (XresB); outputs f32 (outF) and/or bf16 (outB).
__global__ __launch_bounds__(256) void ln_res(const float* __restrict__ planes,
    int np, const float* __restrict__ bias, const float* __restrict__ XresF,
    const u16* __restrict__ XresB, const float* __restrict__ gamma,
    const float* __restrict__ beta, float* __restrict__ outF,
    u16* __restrict__ outB) {
  __shared__ float s1[4], s2[4];
  const int row = blockIdx.x, t = threadIdx.x;
  float4 y = ((const float4*)(planes + (size_t)row * D))[t];
  for (int j = 1; j < np; ++j) {
    const float4 y2 = ((const float4*)(planes + (size_t)j * M * D + (size_t)row * D))[t];
    y.x += y2.x; y.y += y2.y; y.z += y2.z; y.w += y2.w;
  }
  if (bias) {
    const float4 bb = ((const float4*)bias)[t];
    y.x += bb.x; y.y += bb.y; y.z += bb.z; y.w += bb.w;
  }
  float sm = y.x + y.y + y.z + y.w;
  float sq = y.x * y.x + y.y * y.y + y.z * y.z + y.w * y.w;
#pragma unroll
  for (int m2 = 1; m2 <= 32; m2 <<= 1) { sm += __shfl_xor(sm, m2); sq += __shfl_xor(sq, m2); }
  if ((t & 63) == 0) { s1[t >> 6] = sm; s2[t >> 6] = sq; }
  __syncthreads();
  float tot = s1[0] + s1[1] + s1[2] + s1[3];
  float tsq = s2[0] + s2[1] + s2[2] + s2[3];
  float mu = tot * (1.0f / D);
  float var = tsq * (1.0f / D) - mu * mu;
  float rstd = rsqrtf(var + 1e-6f);
  float4 xr;
  if (XresF) {
    xr = ((const float4*)(XresF + (size_t)row * D))[t];
  } else {
    ushort4 xb = ((const ushort4*)(XresB + (size_t)row * D))[t];
    xr.x = bf2f(xb.x); xr.y = bf2f(xb.y); xr.z = bf2f(xb.z); xr.w = bf2f(xb.w);
  }
  const float4 ga = ((const float4*)gamma)[t];
  const float4 be = ((const float4*)beta)[t];
  float4 o;
  o.x = xr.x + (y.x - mu) * rstd * ga.x + be.x;
  o.y = xr.y + (y.y - mu) * rstd * ga.y + be.y;
  o.z = xr.z + (y.z - mu) * rstd * ga.z + be.z;
  o.w = xr.w + (y.w - mu) * rstd * ga.w + be.w;
  if (outF) ((float4*)(outF + (size_t)row * D))[t] = o;
  if (outB) {
    ushort4 ob = make_ushort4(f2bf(o.x), f2bf(o.y), f2bf(o.z), f2bf(o.w));
    ((ushort4*)outB)[(size_t)row * (D / 4) + t] = ob;
  }
}

extern "C" void kernel_launch(void* const* d_in, const int* in_sizes, int n_in,
                              void* d_out, int out_size, void* d_ws, size_t ws_size,
                              hipStream_t stream) {
  const float* X   = (const float*)d_in[0];
  const int*   msk = (const int*)d_in[1];
  const float* WQ  = (const float*)d_in[2];
  const float* WK  = (const float*)d_in[3];
  const float* WV  = (const float*)d_in[4];
  const float* WO  = (const float*)d_in[5];
  const float* W1  = (const float*)d_in[6];
  const float* b1  = (const float*)d_in[7];
  const float* W2  = (const float*)d_in[8];
  const float* b2  = (const float*)d_in[9];
  const float* g1  = (const float*)d_in[10];
  const float* be1 = (const float*)d_in[11];
  const float* g2  = (const float*)d_in[12];
  const float* be2 = (const float*)d_in[13];
  float* out = (float*)d_out;
  const float SCL = 0.18033688011112042f;   // log2(e) / sqrt(DKh)

  char* ws = (char*)d_ws;
  size_t off = 0;
  auto alloc = [&](size_t bytes) {
    void* p = ws + off;
    off += (bytes + 1023) & ~(size_t)1023;
    return p;
  };
  u16* Xb     = (u16*)alloc((size_t)M * D * 2);           // 8 MB
  u16* WQKVt  = (u16*)alloc((size_t)3 * D * D * 2);       // 6 MB
  u16* WOt    = (u16*)alloc((size_t)D * D * 2);           // 2 MB
  u16* W1t    = (u16*)alloc((size_t)DFF * D * 2);         // 8 MB
  u16* W2t    = (u16*)alloc((size_t)D * DFF * 2);         // 8 MB
  u16* QKVb   = (u16*)alloc((size_t)M * 3 * D * 2);       // 24 MB
  u16* Vt     = (u16*)alloc((size_t)B * H * DKh * S * 2); // 8 MB (contiguous after QKVb)
  u16* Ctx    = (u16*)alloc((size_t)M * D * 2);           // 8 MB
  u16* X1b    = (u16*)alloc((size_t)M * D * 2);           // 8 MB (x1, bf16 only)
  u16* Hb     = (u16*)alloc((size_t)M * DFF * 2);         // 32 MB
  // 2-plane split-K scratch aliases QKVb+Vt (32 MB contiguous, dead post-attn).
  float* PP   = (float*)QKVb;
  if (off > ws_size) return;  // mandatory allocs must fit
  // optional dedicated 64 MB for 4-plane split-K of W2
  size_t off4 = off;
  float* PP4 = (float*)(ws + off4);
  off4 += (size_t)4 * M * D * 4;
  const bool split4 = (off4 <= ws_size);

  dim3 blk(256), blk5(512);

  // 1+2. fused prep: X->bf16, all weight transposes, one launch
  prep<<<dim3(7168), blk, 0, stream>>>(X, Xb, WQ, WK, WV, WO, WQKVt, WOt, W1, W1t, W2, W2t);
  // 3. fused QKV projection: [4096][3072]; Q cols (<D) pre-scaled by log2(e)/8
  gemm256<0><<<dim3(3 * D / 256, M / 256), blk5, 0, stream>>>(Xb, WQKVt, QKVb, nullptr, M, 3 * D, D, D, D, SCL);
  // 4. V -> Vt [b,h,dk,s]
  vtrans<<<dim3(S / 64, B * H), blk, 0, stream>>>(QKVb + 2 * D, Vt, 3 * D);
  // 5. attention (2 Q-sets per wave, 128 q/block -> 512 blocks; proven R12 body)
  attn_kernel<<<dim3(S / 128, B * H), blk, 0, stream>>>(QKVb, QKVb + D, Vt, msk, Ctx, 3 * D);
  // 6. O projection, split-K=2 -> planes PP[0..1] (QKVb region dead)
  gemm256<1><<<dim3(D / 256, M / 256, 2), blk5, 0, stream>>>(Ctx, WOt, PP, nullptr, M, D, D, D / 2, 0, 1.0f);
  // 7. x1 = X + LN(AO0+AO1)  (bf16 only)
  ln_res<<<dim3(M), blk, 0, stream>>>(PP, 2, nullptr, X, nullptr, g1, be1, nullptr, X1b);
  // 8. H = relu(x1 @ W1 + b1)
  gemm256<2><<<dim3(DFF / 256, M / 256), blk5, 0, stream>>>(X1b, W1t, Hb, b1, M, DFF, D, D, 0, 1.0f);
  // 9/10. ffn = H @ W2 (split-K), then out = x1 + LN(sum planes + b2)
  if (split4) {
    gemm256<1><<<dim3(D / 256, M / 256, 4), blk5, 0, stream>>>(Hb, W2t, PP4, nullptr, M, D, DFF, DFF / 4, 0, 1.0f);
    ln_res<<<dim3(M), blk, 0, stream>>>(PP4, 4, b2, nullptr, X1b, g2, be2, out, nullptr);
  } else {
    gemm256<1><<<dim3(D / 256, M / 256, 2), blk5, 0, stream>>>(Hb, W2t, PP, nullptr, M, D, DFF, DFF / 2, 0, 1.0f);
    ln_res<<<dim3(M), blk, 0, stream>>>(PP, 2, b2, nullptr, X1b, g2, be2, out, nullptr);
  }
}